// Round 6
// baseline (25774.435 us; speedup 1.0000x reference)
//
#include <hip/hip_runtime.h>

#define Tt 512

// ws float offsets:
//  hg [2][2][256][128] h for layers 0,1 (slot = t&1)        @ 0
//  h2 [256][128]       final h of layer 2                   @ 131072
//  xg [2][2][256][512] gate contribs for layers 1,2 (t&1)   @ 163840
//  flags (unsigned): hf[3][32] @ +0, xf[2][32] @ +96  (160)
#define OFF_HG  0
#define OFF_H2  131072
#define OFF_XG  163840
#define OFF_FLG 688128
// total ~2.75 MB (same footprint as R5, proven to fit ws)

__device__ __forceinline__ float sigm(float v) { return 1.f / (1.f + __expf(-v)); }
__device__ __forceinline__ int fk(int k) { return k + ((k >> 5) << 2); }  // LDS k-swizzle

__device__ __forceinline__ void wait_ge(unsigned* p, unsigned tgt) {
    while (__hip_atomic_load(p, __ATOMIC_RELAXED, __HIP_MEMORY_SCOPE_AGENT) < tgt)
        __builtin_amdgcn_s_sleep(2);
}

__global__ void zero_flags(float* ws) {
    if (threadIdx.x < 160) ((unsigned*)(ws + OFF_FLG))[threadIdx.x] = 0u;
}

__global__ __launch_bounds__(512, 2) void lstm_persistent(
    const float* __restrict__ x,
    const float* __restrict__ Wih0, const float* __restrict__ Whh0,
    const float* __restrict__ bih0, const float* __restrict__ bhh0,
    const float* __restrict__ Wih1, const float* __restrict__ Whh1,
    const float* __restrict__ bih1, const float* __restrict__ bhh1,
    const float* __restrict__ Wih2, const float* __restrict__ Whh2,
    const float* __restrict__ bih2, const float* __restrict__ bhh2,
    float* __restrict__ ws)
{
    unsigned* flg = (unsigned*)(ws + OFF_FLG);
    const int bid = blockIdx.x, tid = threadIdx.x;
    const int wv = tid >> 6, ln = tid & 63;
    const int kq = ln >> 4, cg = ln & 15;        // k-quarter 0..3, col-group 0..15
    const int c0 = (wv * 16 + cg) * 4;           // this thread's 4 gate-cols
    const int k0 = kq * 32;                      // this thread's 32-k slice

    if (bid < 96) {
        // ================= recurrent block: (layer l, row-group g: 8 rows) =================
        const int l = bid >> 5, g = bid & 31, r0 = g * 8;
        const float* Whh = (l == 0) ? Whh0 : (l == 1) ? Whh1 : Whh2;
        const float* bih = (l == 0) ? bih0 : (l == 1) ? bih1 : bih2;
        const float* bhh = (l == 0) ? bhh0 : (l == 1) ? bhh1 : bhh2;

        // Whh slice -> 128 VGPRs (4 cols x 32 k)
        float w[128];
#pragma unroll
        for (int cc = 0; cc < 4; cc++) {
            const float* src = Whh + (size_t)(c0 + cc) * 128 + k0;
#pragma unroll
            for (int j4 = 0; j4 < 8; j4++) {
                float4 v = *(const float4*)(src + 4 * j4);
                w[cc * 32 + 4 * j4]     = v.x; w[cc * 32 + 4 * j4 + 1] = v.y;
                w[cc * 32 + 4 * j4 + 2] = v.z; w[cc * 32 + 4 * j4 + 3] = v.w;
            }
        }
        float wih[32];
        if (l == 0 && kq == 0) {
#pragma unroll
            for (int cc = 0; cc < 4; cc++) {
                float4 v0 = *(const float4*)(Wih0 + (size_t)(c0 + cc) * 8);
                float4 v1 = *(const float4*)(Wih0 + (size_t)(c0 + cc) * 8 + 4);
                wih[cc * 8]     = v0.x; wih[cc * 8 + 1] = v0.y; wih[cc * 8 + 2] = v0.z; wih[cc * 8 + 3] = v0.w;
                wih[cc * 8 + 4] = v1.x; wih[cc * 8 + 5] = v1.y; wih[cc * 8 + 6] = v1.z; wih[cc * 8 + 7] = v1.w;
            }
        }

        // cell mapping: 2 cells/thread: (cr, chc) and (cr+4, chc)
        const int cr = tid >> 7, chc = tid & 127;
        float b4[4];
#pragma unroll
        for (int q = 0; q < 4; q++) b4[q] = bih[q * 128 + chc] + bhh[q * 128 + chc];
        float cs0 = 0.f, cs1 = 0.f;

        __shared__ float sH[2][8][140];   // k-swizzled via fk()
        __shared__ float sG[8][516];
        __shared__ float sX[8][8];
        float* sGf = &sG[0][0];

        unsigned* hf_own = &flg[l * 32 + g];
        unsigned* xf_in  = &flg[96 + (l - 1) * 32 + g];   // valid l>0
        unsigned* xf_bp  = &flg[96 + l * 32 + g];         // valid l<2

        for (int t = 0; t < Tt; ++t) {
            if (tid == 0) {
                if (l > 0)           wait_ge(xf_in, (unsigned)(t + 1));
                if (l < 2 && t >= 2) wait_ge(xf_bp, (unsigned)(t - 1));
                (void)__hip_atomic_load(hf_own, __ATOMIC_ACQUIRE, __HIP_MEMORY_SCOPE_AGENT);
            }
            __syncthreads();

            // early xg loads (latency hidden under GEMM)
            float xg[8];
            if (l > 0) {
                const float* xb = ws + OFF_XG + (size_t)((l - 1) * 2 + (t & 1)) * 131072;
#pragma unroll
                for (int q = 0; q < 4; q++) {
                    xg[q]     = __hip_atomic_load(xb + (size_t)(r0 + cr) * 512 + q * 128 + chc,
                                                  __ATOMIC_RELAXED, __HIP_MEMORY_SCOPE_AGENT);
                    xg[4 + q] = __hip_atomic_load(xb + (size_t)(r0 + cr + 4) * 512 + q * 128 + chc,
                                                  __ATOMIC_RELAXED, __HIP_MEMORY_SCOPE_AGENT);
                }
            } else {
                if (tid < 64)
                    sX[tid >> 3][tid & 7] = x[(size_t)(r0 + (tid >> 3)) * 4096 + t * 8 + (tid & 7)];
                __syncthreads();
            }

            float acc[32];
#pragma unroll
            for (int i = 0; i < 32; i++) acc[i] = 0.f;

            if (t > 0) {
                const float* A = &sH[(t - 1) & 1][0][0];
                const int ka0 = kq * 36;   // fk(k0)
#pragma unroll
                for (int j4 = 0; j4 < 8; j4++) {
#pragma unroll
                    for (int r = 0; r < 8; r++) {
                        float4 a = *(const float4*)(A + r * 140 + ka0 + 4 * j4);
#pragma unroll
                        for (int cc = 0; cc < 4; cc++) {
                            acc[cc * 8 + r] += a.x * w[cc * 32 + 4 * j4]
                                             + a.y * w[cc * 32 + 4 * j4 + 1]
                                             + a.z * w[cc * 32 + 4 * j4 + 2]
                                             + a.w * w[cc * 32 + 4 * j4 + 3];
                        }
                    }
                }
            }
            if (l == 0 && kq == 0) {
#pragma unroll
                for (int i = 0; i < 8; i++)
#pragma unroll
                    for (int r = 0; r < 8; r++) {
                        float xv = sX[r][i];
#pragma unroll
                        for (int cc = 0; cc < 4; cc++) acc[cc * 8 + r] += xv * wih[cc * 8 + i];
                    }
            }
            // reduce over kq (lanes 16 apart)
#pragma unroll
            for (int i = 0; i < 32; i++) {
                acc[i] += __shfl_xor(acc[i], 16);
                acc[i] += __shfl_xor(acc[i], 32);
            }
            if (ln < 16) {
#pragma unroll
                for (int r = 0; r < 8; r++)
                    *(float4*)(sGf + r * 516 + c0) =
                        make_float4(acc[r], acc[8 + r], acc[16 + r], acc[24 + r]);
            }
            __syncthreads();

            // ---- cell update ----
            float* hw = ws + OFF_HG + (size_t)(l * 2 + (t & 1)) * 32768;
            {
                float gi = sGf[cr * 516 + chc]       + b4[0];
                float gf = sGf[cr * 516 + 128 + chc] + b4[1];
                float gg = sGf[cr * 516 + 256 + chc] + b4[2];
                float go = sGf[cr * 516 + 384 + chc] + b4[3];
                if (l > 0) { gi += xg[0]; gf += xg[1]; gg += xg[2]; go += xg[3]; }
                float cn = sigm(gf) * cs0 + sigm(gi) * tanhf(gg);
                cs0 = cn;
                float h = sigm(go) * tanhf(cn);
                sH[t & 1][cr][fk(chc)] = h;
                if (l < 2)
                    __hip_atomic_store(hw + (size_t)(r0 + cr) * 128 + chc, h,
                                       __ATOMIC_RELAXED, __HIP_MEMORY_SCOPE_AGENT);
                else if (t == Tt - 1)
                    ws[OFF_H2 + (size_t)(r0 + cr) * 128 + chc] = h;
            }
            {
                int r2 = cr + 4;
                float gi = sGf[r2 * 516 + chc]       + b4[0];
                float gf = sGf[r2 * 516 + 128 + chc] + b4[1];
                float gg = sGf[r2 * 516 + 256 + chc] + b4[2];
                float go = sGf[r2 * 516 + 384 + chc] + b4[3];
                if (l > 0) { gi += xg[4]; gf += xg[5]; gg += xg[6]; go += xg[7]; }
                float cn = sigm(gf) * cs1 + sigm(gi) * tanhf(gg);
                cs1 = cn;
                float h = sigm(go) * tanhf(cn);
                sH[t & 1][r2][fk(chc)] = h;
                if (l < 2)
                    __hip_atomic_store(hw + (size_t)(r0 + r2) * 128 + chc, h,
                                       __ATOMIC_RELAXED, __HIP_MEMORY_SCOPE_AGENT);
                else if (t == Tt - 1)
                    ws[OFF_H2 + (size_t)(r0 + r2) * 128 + chc] = h;
            }
            __syncthreads();   // drain h stores + sG reuse safety
            if (tid == 0)
                __hip_atomic_store(hf_own, (unsigned)(t + 1), __ATOMIC_RELEASE, __HIP_MEMORY_SCOPE_AGENT);
        }
    } else {
        // ================= input-GEMM block: (layer l in {1,2}, group g) =================
        const int e = bid - 96;
        const int l = 1 + (e >> 5), g = e & 31, r0 = g * 8;
        const float* Wih = (l == 1) ? Wih1 : Wih2;

        float w[128];
#pragma unroll
        for (int cc = 0; cc < 4; cc++) {
            const float* src = Wih + (size_t)(c0 + cc) * 128 + k0;
#pragma unroll
            for (int j4 = 0; j4 < 8; j4++) {
                float4 v = *(const float4*)(src + 4 * j4);
                w[cc * 32 + 4 * j4]     = v.x; w[cc * 32 + 4 * j4 + 1] = v.y;
                w[cc * 32 + 4 * j4 + 2] = v.z; w[cc * 32 + 4 * j4 + 3] = v.w;
            }
        }

        __shared__ float sA[8][140];
        unsigned* hf_in  = &flg[(l - 1) * 32 + g];
        unsigned* hf_bp  = &flg[l * 32 + g];
        unsigned* xf_own = &flg[96 + (l - 1) * 32 + g];
        const int sr = tid >> 7, shc = tid & 127;

        for (int t = 0; t < Tt; ++t) {
            if (tid == 0) {
                wait_ge(hf_in, (unsigned)(t + 1));
                if (t >= 2) wait_ge(hf_bp, (unsigned)(t - 1));
                (void)__hip_atomic_load(hf_in, __ATOMIC_ACQUIRE, __HIP_MEMORY_SCOPE_AGENT);
            }
            __syncthreads();

            const float* hgp = ws + OFF_HG + (size_t)((l - 1) * 2 + (t & 1)) * 32768;
            sA[sr][fk(shc)] = __hip_atomic_load(hgp + (size_t)(r0 + sr) * 128 + shc,
                                                __ATOMIC_RELAXED, __HIP_MEMORY_SCOPE_AGENT);
            sA[sr + 4][fk(shc)] = __hip_atomic_load(hgp + (size_t)(r0 + sr + 4) * 128 + shc,
                                                    __ATOMIC_RELAXED, __HIP_MEMORY_SCOPE_AGENT);
            __syncthreads();

            float acc[32];
#pragma unroll
            for (int i = 0; i < 32; i++) acc[i] = 0.f;
            {
                const float* A = &sA[0][0];
                const int ka0 = kq * 36;
#pragma unroll
                for (int j4 = 0; j4 < 8; j4++) {
#pragma unroll
                    for (int r = 0; r < 8; r++) {
                        float4 a = *(const float4*)(A + r * 140 + ka0 + 4 * j4);
#pragma unroll
                        for (int cc = 0; cc < 4; cc++) {
                            acc[cc * 8 + r] += a.x * w[cc * 32 + 4 * j4]
                                             + a.y * w[cc * 32 + 4 * j4 + 1]
                                             + a.z * w[cc * 32 + 4 * j4 + 2]
                                             + a.w * w[cc * 32 + 4 * j4 + 3];
                        }
                    }
                }
            }
#pragma unroll
            for (int i = 0; i < 32; i++) {
                acc[i] += __shfl_xor(acc[i], 16);
                acc[i] += __shfl_xor(acc[i], 32);
            }
            if (ln < 16) {
                float* xb = ws + OFF_XG + (size_t)((l - 1) * 2 + (t & 1)) * 131072;
#pragma unroll
                for (int r = 0; r < 8; r++)
#pragma unroll
                    for (int cc = 0; cc < 4; cc++)
                        __hip_atomic_store(xb + (size_t)(r0 + r) * 512 + c0 + cc, acc[cc * 8 + r],
                                           __ATOMIC_RELAXED, __HIP_MEMORY_SCOPE_AGENT);
            }
            __syncthreads();   // drain xg stores
            if (tid == 0)
                __hip_atomic_store(xf_own, (unsigned)(t + 1), __ATOMIC_RELEASE, __HIP_MEMORY_SCOPE_AGENT);
        }
    }
}

__global__ void fc_kernel(const float* __restrict__ ws, const float* __restrict__ Wfc,
                          const float* __restrict__ bfc, float* __restrict__ out)
{
    const float* h2 = ws + OFF_H2;
    int b = threadIdx.x;   // 256 threads
    float a0 = bfc[0], a1 = bfc[1], a2 = bfc[2];
    for (int k = 0; k < 128; k++) {
        float h = h2[b * 128 + k];
        a0 += h * Wfc[0 * 128 + k];
        a1 += h * Wfc[1 * 128 + k];
        a2 += h * Wfc[2 * 128 + k];
    }
    out[b * 3 + 0] = a0;
    out[b * 3 + 1] = a1;
    out[b * 3 + 2] = a2;
}

extern "C" void kernel_launch(void* const* d_in, const int* in_sizes, int n_in,
                              void* d_out, int out_size, void* d_ws, size_t ws_size,
                              hipStream_t stream)
{
    const float* x = (const float*)d_in[0];
    float* ws = (float*)d_ws;

    zero_flags<<<1, 256, 0, stream>>>(ws);

    lstm_persistent<<<160, 512, 0, stream>>>(
        x,
        (const float*)d_in[1],  (const float*)d_in[2],  (const float*)d_in[3],  (const float*)d_in[4],
        (const float*)d_in[5],  (const float*)d_in[6],  (const float*)d_in[7],  (const float*)d_in[8],
        (const float*)d_in[9],  (const float*)d_in[10], (const float*)d_in[11], (const float*)d_in[12],
        ws);

    fc_kernel<<<1, 256, 0, stream>>>(ws, (const float*)d_in[13], (const float*)d_in[14], (float*)d_out);
}

// Round 7
// 25040.427 us; speedup vs baseline: 1.0293x; 1.0293x over previous
//
#include <hip/hip_runtime.h>

#define Tt 512

// ws float offsets:
//  hg [2][2][256][128] h for layers 0,1 (slot = t&1)        @ 0
//  h2 [256][128]       final h of layer 2                   @ 131072
//  xg [2][2][256][512] gate contribs for layers 1,2 (t&1)   @ 163840
//  flags (unsigned): hf[3][32] @ +0, xf[2][32] @ +96  (160)
#define OFF_HG  0
#define OFF_H2  131072
#define OFF_XG  163840
#define OFF_FLG 688128
// total ~2.75 MB (proven to fit ws)

__device__ __forceinline__ float sigm(float v) { return 1.f / (1.f + __expf(-v)); }
__device__ __forceinline__ int fk(int k) { return k + ((k >> 5) << 2); }  // LDS k-swizzle

__device__ __forceinline__ void wait_ge(unsigned* p, unsigned tgt) {
    while (__hip_atomic_load(p, __ATOMIC_RELAXED, __HIP_MEMORY_SCOPE_AGENT) < tgt)
        __builtin_amdgcn_s_sleep(2);
}

__global__ void zero_flags(float* ws) {
    if (threadIdx.x < 160) ((unsigned*)(ws + OFF_FLG))[threadIdx.x] = 0u;
}

// waves_per_eu(2,2): pin allocator budget to 256 VGPR/wave (2 waves/EU).
// R5 (cap 64) and R6 (cap 128) both spilled w[128] -> 19-20 GB scratch FETCH.
__global__ __launch_bounds__(512)
__attribute__((amdgpu_waves_per_eu(2, 2)))
void lstm_persistent(
    const float* __restrict__ x,
    const float* __restrict__ Wih0, const float* __restrict__ Whh0,
    const float* __restrict__ bih0, const float* __restrict__ bhh0,
    const float* __restrict__ Wih1, const float* __restrict__ Whh1,
    const float* __restrict__ bih1, const float* __restrict__ bhh1,
    const float* __restrict__ Wih2, const float* __restrict__ Whh2,
    const float* __restrict__ bih2, const float* __restrict__ bhh2,
    float* __restrict__ ws)
{
    unsigned* flg = (unsigned*)(ws + OFF_FLG);
    const int bid = blockIdx.x, tid = threadIdx.x;
    const int wv = tid >> 6, ln = tid & 63;
    const int kq = ln >> 4, cg = ln & 15;        // k-quarter 0..3, col-group 0..15
    const int c0 = (wv * 16 + cg) * 4;           // this thread's 4 gate-cols
    const int k0 = kq * 32;                      // this thread's 32-k slice

    if (bid < 96) {
        // ================= recurrent block: (layer l, row-group g: 8 rows) =================
        const int l = bid >> 5, g = bid & 31, r0 = g * 8;
        const float* Whh = (l == 0) ? Whh0 : (l == 1) ? Whh1 : Whh2;
        const float* bih = (l == 0) ? bih0 : (l == 1) ? bih1 : bih2;
        const float* bhh = (l == 0) ? bhh0 : (l == 1) ? bhh1 : bhh2;

        // Whh slice -> 128 VGPRs (4 cols x 32 k)
        float w[128];
#pragma unroll
        for (int cc = 0; cc < 4; cc++) {
            const float* src = Whh + (size_t)(c0 + cc) * 128 + k0;
#pragma unroll
            for (int j4 = 0; j4 < 8; j4++) {
                float4 v = *(const float4*)(src + 4 * j4);
                w[cc * 32 + 4 * j4]     = v.x; w[cc * 32 + 4 * j4 + 1] = v.y;
                w[cc * 32 + 4 * j4 + 2] = v.z; w[cc * 32 + 4 * j4 + 3] = v.w;
            }
        }
        float wih[32];
        if (l == 0 && kq == 0) {
#pragma unroll
            for (int cc = 0; cc < 4; cc++) {
                float4 v0 = *(const float4*)(Wih0 + (size_t)(c0 + cc) * 8);
                float4 v1 = *(const float4*)(Wih0 + (size_t)(c0 + cc) * 8 + 4);
                wih[cc * 8]     = v0.x; wih[cc * 8 + 1] = v0.y; wih[cc * 8 + 2] = v0.z; wih[cc * 8 + 3] = v0.w;
                wih[cc * 8 + 4] = v1.x; wih[cc * 8 + 5] = v1.y; wih[cc * 8 + 6] = v1.z; wih[cc * 8 + 7] = v1.w;
            }
        }

        // cell mapping: 2 cells/thread: (cr, chc) and (cr+4, chc)
        const int cr = tid >> 7, chc = tid & 127;
        float b4[4];
#pragma unroll
        for (int q = 0; q < 4; q++) b4[q] = bih[q * 128 + chc] + bhh[q * 128 + chc];
        float cs0 = 0.f, cs1 = 0.f;

        __shared__ float sH[2][8][140];   // k-swizzled via fk()
        __shared__ float sG[8][516];
        __shared__ float sX[8][8];
        float* sGf = &sG[0][0];

        unsigned* hf_own = &flg[l * 32 + g];
        unsigned* xf_in  = &flg[96 + (l - 1) * 32 + g];   // valid l>0
        unsigned* xf_bp  = &flg[96 + l * 32 + g];         // valid l<2

        for (int t = 0; t < Tt; ++t) {
            if (tid == 0) {
                if (l > 0)           wait_ge(xf_in, (unsigned)(t + 1));
                if (l < 2 && t >= 2) wait_ge(xf_bp, (unsigned)(t - 1));
                (void)__hip_atomic_load(hf_own, __ATOMIC_ACQUIRE, __HIP_MEMORY_SCOPE_AGENT);
            }
            __syncthreads();

            // early xg loads (latency hidden under GEMM)
            float xg[8];
            if (l > 0) {
                const float* xb = ws + OFF_XG + (size_t)((l - 1) * 2 + (t & 1)) * 131072;
#pragma unroll
                for (int q = 0; q < 4; q++) {
                    xg[q]     = __hip_atomic_load(xb + (size_t)(r0 + cr) * 512 + q * 128 + chc,
                                                  __ATOMIC_RELAXED, __HIP_MEMORY_SCOPE_AGENT);
                    xg[4 + q] = __hip_atomic_load(xb + (size_t)(r0 + cr + 4) * 512 + q * 128 + chc,
                                                  __ATOMIC_RELAXED, __HIP_MEMORY_SCOPE_AGENT);
                }
            } else {
                if (tid < 64)
                    sX[tid >> 3][tid & 7] = x[(size_t)(r0 + (tid >> 3)) * 4096 + t * 8 + (tid & 7)];
                __syncthreads();
            }

            float acc[32];
#pragma unroll
            for (int i = 0; i < 32; i++) acc[i] = 0.f;

            if (t > 0) {
                const float* A = &sH[(t - 1) & 1][0][0];
                const int ka0 = kq * 36;   // fk(k0)
#pragma unroll
                for (int j4 = 0; j4 < 8; j4++) {
#pragma unroll
                    for (int r = 0; r < 8; r++) {
                        float4 a = *(const float4*)(A + r * 140 + ka0 + 4 * j4);
#pragma unroll
                        for (int cc = 0; cc < 4; cc++) {
                            acc[cc * 8 + r] += a.x * w[cc * 32 + 4 * j4]
                                             + a.y * w[cc * 32 + 4 * j4 + 1]
                                             + a.z * w[cc * 32 + 4 * j4 + 2]
                                             + a.w * w[cc * 32 + 4 * j4 + 3];
                        }
                    }
                }
            }
            if (l == 0 && kq == 0) {
#pragma unroll
                for (int i = 0; i < 8; i++)
#pragma unroll
                    for (int r = 0; r < 8; r++) {
                        float xv = sX[r][i];
#pragma unroll
                        for (int cc = 0; cc < 4; cc++) acc[cc * 8 + r] += xv * wih[cc * 8 + i];
                    }
            }
            // reduce over kq (lanes 16 apart)
#pragma unroll
            for (int i = 0; i < 32; i++) {
                acc[i] += __shfl_xor(acc[i], 16);
                acc[i] += __shfl_xor(acc[i], 32);
            }
            if (ln < 16) {
#pragma unroll
                for (int r = 0; r < 8; r++)
                    *(float4*)(sGf + r * 516 + c0) =
                        make_float4(acc[r], acc[8 + r], acc[16 + r], acc[24 + r]);
            }
            __syncthreads();

            // ---- cell update ----
            float* hw = ws + OFF_HG + (size_t)(l * 2 + (t & 1)) * 32768;
            {
                float gi = sGf[cr * 516 + chc]       + b4[0];
                float gf = sGf[cr * 516 + 128 + chc] + b4[1];
                float gg = sGf[cr * 516 + 256 + chc] + b4[2];
                float go = sGf[cr * 516 + 384 + chc] + b4[3];
                if (l > 0) { gi += xg[0]; gf += xg[1]; gg += xg[2]; go += xg[3]; }
                float cn = sigm(gf) * cs0 + sigm(gi) * tanhf(gg);
                cs0 = cn;
                float h = sigm(go) * tanhf(cn);
                sH[t & 1][cr][fk(chc)] = h;
                if (l < 2)
                    __hip_atomic_store(hw + (size_t)(r0 + cr) * 128 + chc, h,
                                       __ATOMIC_RELAXED, __HIP_MEMORY_SCOPE_AGENT);
                else if (t == Tt - 1)
                    ws[OFF_H2 + (size_t)(r0 + cr) * 128 + chc] = h;
            }
            {
                int r2 = cr + 4;
                float gi = sGf[r2 * 516 + chc]       + b4[0];
                float gf = sGf[r2 * 516 + 128 + chc] + b4[1];
                float gg = sGf[r2 * 516 + 256 + chc] + b4[2];
                float go = sGf[r2 * 516 + 384 + chc] + b4[3];
                if (l > 0) { gi += xg[4]; gf += xg[5]; gg += xg[6]; go += xg[7]; }
                float cn = sigm(gf) * cs1 + sigm(gi) * tanhf(gg);
                cs1 = cn;
                float h = sigm(go) * tanhf(cn);
                sH[t & 1][r2][fk(chc)] = h;
                if (l < 2)
                    __hip_atomic_store(hw + (size_t)(r0 + r2) * 128 + chc, h,
                                       __ATOMIC_RELAXED, __HIP_MEMORY_SCOPE_AGENT);
                else if (t == Tt - 1)
                    ws[OFF_H2 + (size_t)(r0 + r2) * 128 + chc] = h;
            }
            __syncthreads();   // drain h stores + sG reuse safety
            if (tid == 0)
                __hip_atomic_store(hf_own, (unsigned)(t + 1), __ATOMIC_RELEASE, __HIP_MEMORY_SCOPE_AGENT);
        }
    } else {
        // ================= input-GEMM block: (layer l in {1,2}, group g) =================
        const int e = bid - 96;
        const int l = 1 + (e >> 5), g = e & 31, r0 = g * 8;
        const float* Wih = (l == 1) ? Wih1 : Wih2;

        float w[128];
#pragma unroll
        for (int cc = 0; cc < 4; cc++) {
            const float* src = Wih + (size_t)(c0 + cc) * 128 + k0;
#pragma unroll
            for (int j4 = 0; j4 < 8; j4++) {
                float4 v = *(const float4*)(src + 4 * j4);
                w[cc * 32 + 4 * j4]     = v.x; w[cc * 32 + 4 * j4 + 1] = v.y;
                w[cc * 32 + 4 * j4 + 2] = v.z; w[cc * 32 + 4 * j4 + 3] = v.w;
            }
        }

        __shared__ float sA[8][140];
        unsigned* hf_in  = &flg[(l - 1) * 32 + g];
        unsigned* hf_bp  = &flg[l * 32 + g];
        unsigned* xf_own = &flg[96 + (l - 1) * 32 + g];
        const int sr = tid >> 7, shc = tid & 127;

        for (int t = 0; t < Tt; ++t) {
            if (tid == 0) {
                wait_ge(hf_in, (unsigned)(t + 1));
                if (t >= 2) wait_ge(hf_bp, (unsigned)(t - 1));
                (void)__hip_atomic_load(hf_in, __ATOMIC_ACQUIRE, __HIP_MEMORY_SCOPE_AGENT);
            }
            __syncthreads();

            const float* hgp = ws + OFF_HG + (size_t)((l - 1) * 2 + (t & 1)) * 32768;
            sA[sr][fk(shc)] = __hip_atomic_load(hgp + (size_t)(r0 + sr) * 128 + shc,
                                                __ATOMIC_RELAXED, __HIP_MEMORY_SCOPE_AGENT);
            sA[sr + 4][fk(shc)] = __hip_atomic_load(hgp + (size_t)(r0 + sr + 4) * 128 + shc,
                                                    __ATOMIC_RELAXED, __HIP_MEMORY_SCOPE_AGENT);
            __syncthreads();

            float acc[32];
#pragma unroll
            for (int i = 0; i < 32; i++) acc[i] = 0.f;
            {
                const float* A = &sA[0][0];
                const int ka0 = kq * 36;
#pragma unroll
                for (int j4 = 0; j4 < 8; j4++) {
#pragma unroll
                    for (int r = 0; r < 8; r++) {
                        float4 a = *(const float4*)(A + r * 140 + ka0 + 4 * j4);
#pragma unroll
                        for (int cc = 0; cc < 4; cc++) {
                            acc[cc * 8 + r] += a.x * w[cc * 32 + 4 * j4]
                                             + a.y * w[cc * 32 + 4 * j4 + 1]
                                             + a.z * w[cc * 32 + 4 * j4 + 2]
                                             + a.w * w[cc * 32 + 4 * j4 + 3];
                        }
                    }
                }
            }
#pragma unroll
            for (int i = 0; i < 32; i++) {
                acc[i] += __shfl_xor(acc[i], 16);
                acc[i] += __shfl_xor(acc[i], 32);
            }
            if (ln < 16) {
                float* xb = ws + OFF_XG + (size_t)((l - 1) * 2 + (t & 1)) * 131072;
#pragma unroll
                for (int r = 0; r < 8; r++)
#pragma unroll
                    for (int cc = 0; cc < 4; cc++)
                        __hip_atomic_store(xb + (size_t)(r0 + r) * 512 + c0 + cc, acc[cc * 8 + r],
                                           __ATOMIC_RELAXED, __HIP_MEMORY_SCOPE_AGENT);
            }
            __syncthreads();   // drain xg stores
            if (tid == 0)
                __hip_atomic_store(xf_own, (unsigned)(t + 1), __ATOMIC_RELEASE, __HIP_MEMORY_SCOPE_AGENT);
        }
    }
}

__global__ void fc_kernel(const float* __restrict__ ws, const float* __restrict__ Wfc,
                          const float* __restrict__ bfc, float* __restrict__ out)
{
    const float* h2 = ws + OFF_H2;
    int b = threadIdx.x;   // 256 threads
    float a0 = bfc[0], a1 = bfc[1], a2 = bfc[2];
    for (int k = 0; k < 128; k++) {
        float h = h2[b * 128 + k];
        a0 += h * Wfc[0 * 128 + k];
        a1 += h * Wfc[1 * 128 + k];
        a2 += h * Wfc[2 * 128 + k];
    }
    out[b * 3 + 0] = a0;
    out[b * 3 + 1] = a1;
    out[b * 3 + 2] = a2;
}

extern "C" void kernel_launch(void* const* d_in, const int* in_sizes, int n_in,
                              void* d_out, int out_size, void* d_ws, size_t ws_size,
                              hipStream_t stream)
{
    const float* x = (const float*)d_in[0];
    float* ws = (float*)d_ws;

    zero_flags<<<1, 256, 0, stream>>>(ws);

    lstm_persistent<<<160, 512, 0, stream>>>(
        x,
        (const float*)d_in[1],  (const float*)d_in[2],  (const float*)d_in[3],  (const float*)d_in[4],
        (const float*)d_in[5],  (const float*)d_in[6],  (const float*)d_in[7],  (const float*)d_in[8],
        (const float*)d_in[9],  (const float*)d_in[10], (const float*)d_in[11], (const float*)d_in[12],
        ws);

    fc_kernel<<<1, 256, 0, stream>>>(ws, (const float*)d_in[13], (const float*)d_in[14], (float*)d_out);
}